// Round 12
// baseline (31.785 us; speedup 1.0000x reference)
//
#include <hip/hip_runtime.h>
#include <math.h>

#define NJ 128
#define HH 512
#define WW 512
#define FEPS 1e-7f
#define QT  32          // quad tile edge (quads per block side)
#define THS (QT + 2)    // 34: tile + 1-cell halo
#define TLP 36          // padded LDS row pitch

// ---------------------------------------------------------------- eig helper
// 2x2 symmetric eigendecomposition, ascending order (matches jnp.linalg.eigh).
// Bit-identical to validated rounds 2-11.
__device__ __forceinline__ void eig2x2(float a, float b, float c,
                                       float& l0, float& l1,
                                       float& V00, float& V10, float& V01, float& V11) {
    float mean = 0.5f * (a + c);
    float diff = 0.5f * (a - c);
    float disc = sqrtf(diff * diff + b * b);
    l0 = mean - disc;   // smaller
    l1 = mean + disc;   // larger
    float ux, uy;
    if (diff >= 0.f) { ux = diff + disc; uy = b; }
    else             { ux = b;           uy = disc - diff; }
    float nn = sqrtf(ux * ux + uy * uy);
    if (nn > 0.f) { ux /= nn; uy /= nn; } else { ux = 1.f; uy = 0.f; }
    V00 = -uy; V10 = ux;   // column 0 (l0)
    V01 =  ux; V11 = uy;   // column 1 (l1)
}

// ---------------------------------------------------------------- fused vor+markers
// 256 blocks x 1024 threads, one 32x32-quad tile each. Phases:
//   (1) all 128 Gaussian params -> LDS (validated setup math)
//   (2) 34x34 halo tile of val/vor computed IN LDS (validated k_vorf argmin,
//       +13% redundancy across blocks; no global val/vor at all)
//   (3) validated marker/bilinear/Laplacian phase, 1 quad/thread
//   (4) wave segmented prefix-max -> per-block LDS dedup -> <=128 padded
//       global atomics (the round-9 atomic structure)
__global__ __launch_bounds__(1024) void k_fused(
        const float* __restrict__ mu, const float* __restrict__ sigma,
        const int* __restrict__ label, const float* __restrict__ pos_thres,
        const float* __restrict__ neg_thres,
        unsigned* __restrict__ gml) {
    __shared__ float4   lp[NJ];     // mmx, mmy, ia, ib2
    __shared__ float    lic[NJ];    // ic
    __shared__ float4   lvv[NJ];    // V00, V10, V01, V11
    __shared__ float2   lmu[NJ];    // mux, muy
    __shared__ float    lpt[NJ], lnt[NJ];
    __shared__ float    tval[THS][TLP];
    __shared__ int      tvor[THS][TLP];
    __shared__ unsigned lm0[NJ], lm1[NJ];
    __shared__ int      lflag[NJ];

    int tid = threadIdx.x;
    // ---- phase 1: per-block param setup (identical arithmetic in every block)
    if (tid < NJ) {
        int j = tid;
        float a = sigma[j * 4 + 0];
        float b = sigma[j * 4 + 1];
        float c = sigma[j * 4 + 3];
        float l0, l1, V00, V10, V01, V11;
        eig2x2(a, b, c, l0, l1, V00, V10, V01, V11);
        float gmean = sqrtf(l0 * l1);
        float lsc0 = l0 / gmean * 4096.f;
        float lsc1 = l1 / gmean * 4096.f;
        float s00 = (V00 * V00 * lsc0 + V01 * V01 * lsc1) * 0.25f;
        float s01 = (V00 * V10 * lsc0 + V01 * V11 * lsc1) * 0.25f;
        float s11 = (V10 * V10 * lsc0 + V11 * V11 * lsc1) * 0.25f;
        float det = s00 * s11 - s01 * s01;
        float4 q;
        q.x = rintf(mu[j * 2 + 0] * 0.5f);   // jnp.round = ties-to-even = rintf
        q.y = rintf(mu[j * 2 + 1] * 0.5f);
        q.z =  s11 / det;                    // ia
        q.w = -2.f * s01 / det;              // ib2
        lp[j]  = q;
        lic[j] = s00 / det;                  // ic
        lvv[j] = make_float4(V00, V10, V01, V11);
        lmu[j] = make_float2(mu[j * 2 + 0], mu[j * 2 + 1]);
        int cl = label[j];
        lpt[j] = pos_thres[cl];
        lnt[j] = neg_thres[cl];
        lm0[j] = 0u; lm1[j] = 0u; lflag[j] = 0;
    }
    __syncthreads();

    int A0 = (blockIdx.x >> 4) * QT;   // 16x16 tiles of 32x32 quads
    int B0 = (blockIdx.x & 15) * QT;

    // ---- phase 2: 34x34 halo tile of val/vor in LDS (validated argmin math;
    //      OOB cells -> 0/0, never consumed — same semantics as staged zeros)
    const float SCALE = 512.0f / 511.0f;   // linspace(0, 512, 512) step
    for (int idx = tid; idx < THS * THS; idx += 1024) {
        int hu = idx / THS, hw = idx - hu * THS;
        int ca = A0 + hu - 1, cb = B0 + hw - 1;
        float vo = 0.f; int jo = 0;
        if (ca >= 0 && ca < HH && cb >= 0 && cb < WW) {
            float xc = (float)cb * SCALE;
            float yr = (float)ca * SCALE;
            float best = 3.4e38f; int bj = 0;
            #pragma unroll 4
            for (int j = 0; j < NJ; ++j) {
                float4 p = lp[j];
                float ic = lic[j];
                float dx = xc - p.x;
                float dy = yr - p.y;
                // identical expression shape to validated k_vorf (qA)
                float q = p.z * dx * dx + p.w * dx * dy + ic * dy * dy;
                if (q < best) { best = q; bj = j; }   // first index on ties
            }
            vo = expf(-0.5f * best); jo = bj;
        }
        tval[hu][hw] = vo; tvor[hu][hw] = jo;
    }
    __syncthreads();

    // ---- phase 3+4: markers (validated round 11, 1 quad/thread)
    int lane = tid & 63;
    {
        int u = tid >> 5;                    // 0..31
        int v = tid & 31;                    // 0..31
        int a = A0 + u, b = B0 + v;
        bool aM = a > 0, aP = a < 511, bM = b > 0, bP = b < 511;
        int hmm_ = (aM && bM) ? tvor[u    ][v    ] : 0;
        int hm0_ =  aM        ? tvor[u    ][v + 1] : 0;
        int hm1_ = (aM && bP) ? tvor[u    ][v + 2] : 0;
        int h0m_ =  bM        ? tvor[u + 1][v    ] : 0;
        int h00_ =              tvor[u + 1][v + 1];
        int h0p_ =  bP        ? tvor[u + 1][v + 2] : 0;
        int hpm_ = (aP && bM) ? tvor[u + 2][v    ] : 0;
        int hp0_ =  aP        ? tvor[u + 2][v + 1] : 0;
        int hpp_ = (aP && bP) ? tvor[u + 2][v + 2] : 0;
        // exact-int Laplacian (3x3 ones, center -8, zero-padded) per full-res pixel
        int lap00 = -5 * h00_ + hmm_ + 2 * hm0_ + 2 * h0m_;
        int lap01 = -5 * h00_ + 2 * hm0_ + hm1_ + 2 * h0p_;
        int lap10 = -5 * h00_ + 2 * h0m_ + hpm_ + 2 * hp0_;
        int lap11 = -5 * h00_ + 2 * h0p_ + 2 * hp0_ + hpp_;
        int hv = h00_;
        float  pt = lpt[hv], nt = lnt[hv];
        float4 Vv = lvv[hv];
        float2 mv = lmu[hv];
        float m0 = -1.f, m1 = -1.f;   // r0,r1 >= 0, so -1 == "no valid pixel yet"

#define DO_PIXEL(U, V, LAP) {                                                  \
    int i = 2 * a + (U), jx = 2 * b + (V);                                     \
    float ry = ((float)i  * 511.0f) / 1023.0f;                                 \
    float rx = ((float)jx * 511.0f) / 1023.0f;                                 \
    int y0 = (int)ry; int y1 = min(y0 + 1, 511); float wy = ry - (float)y0;    \
    int x0 = (int)rx; int x1 = min(x0 + 1, 511); float wx = rx - (float)x0;    \
    int ly0 = y0 - A0 + 1, ly1 = y1 - A0 + 1;                                  \
    int lx0 = x0 - B0 + 1, lx1 = x1 - B0 + 1;                                  \
    float top = tval[ly0][lx0] * (1.f - wx) + tval[ly0][lx1] * wx;             \
    float bot = tval[ly1][lx0] * (1.f - wx) + tval[ly1][lx1] * wx;             \
    float vf  = top * (1.f - wy) + bot * wy;                                   \
    int mk = hv + 1;                                                           \
    if (vf < pt)     mk = 0;                                                   \
    if (vf < nt)     mk = NJ + 1;                                              \
    if ((LAP) != 0)  mk = NJ + 1;                                              \
    if (mk >= 1 && mk <= NJ) {                                                 \
        float dx = (float)jx - mv.x, dy = (float)i - mv.y;                     \
        float r0 = fabsf(Vv.x * dx + Vv.y * dy);                               \
        float r1 = fabsf(Vv.z * dx + Vv.w * dy);                               \
        m0 = fmaxf(m0, r0); m1 = fmaxf(m1, r1);                                \
    } }

        DO_PIXEL(0, 0, lap00)
        DO_PIXEL(0, 1, lap01)
        DO_PIXEL(1, 0, lap10)
        DO_PIXEL(1, 1, lap11)
#undef DO_PIXEL

        // wave segmented prefix-max over contiguous equal-inst runs (validated)
        int inst = (m0 >= 0.f) ? hv : -1;
        #pragma unroll
        for (int d = 1; d < 64; d <<= 1) {
            int   oi = __shfl_up(inst, d);
            float o0 = __shfl_up(m0, d);
            float o1 = __shfl_up(m1, d);
            if (lane >= d && oi == inst) { m0 = fmaxf(m0, o0); m1 = fmaxf(m1, o1); }
        }
        int ni = __shfl_down(inst, 1);
        bool leader = (inst >= 0) && (lane == 63 || ni != inst);
        if (leader) {   // few per wave -> cheap LDS atomics, on-CU
            atomicMax(&lm0[inst], __float_as_uint(m0));
            atomicMax(&lm1[inst], __float_as_uint(m1));
            lflag[inst] = 1;    // benign race, same value
        }
    }
    __syncthreads();

    // one global atomic triple per touched instance per block, padded lines
    if (tid < NJ && lflag[tid]) {
        atomicMax(&gml[tid * 16 + 0], lm0[tid]);
        atomicMax(&gml[tid * 16 + 1], lm1[tid]);
        gml[tid * 16 + 2] = 1u;   // benign race, same value; visible at dispatch end
    }
}

// ---------------------------------------------------------------- K3: loss + bottom-122 mean
// VERBATIM round 11 (validated rank-select version).
__global__ __launch_bounds__(128) void k_loss(
        const float* __restrict__ sigma, const unsigned* __restrict__ gml,
        float* __restrict__ out) {
    __shared__ float lb[NJ];
    __shared__ float wtot[2], wtop[2];
    int j = threadIdx.x;

    float aa = sigma[j * 4 + 0];
    float bb = sigma[j * 4 + 1];
    float cc = sigma[j * 4 + 3];
    float ls0, ls1, V00, V10, V01, V11;
    eig2x2(aa, bb, cc, ls0, ls1, V00, V10, V01, V11);
    float g0 = __uint_as_float(gml[j * 16 + 0]);
    float g1 = __uint_as_float(gml[j * 16 + 1]);
    bool has = gml[j * 16 + 2] > 0u;
    float lt0 = has ? g0 * g0 : ls0;
    float lt1 = has ? g1 * g1 : ls1;
    float whr = (ls0 + ls1) + (lt0 + lt1);
    float tr  = ls0 * lt0 + ls1 * lt1;
    float det_sqrt = sqrtf(fmaxf((ls0 * ls1) * (lt0 * lt1), FEPS));
    whr = whr - 2.f * sqrtf(fmaxf(tr + 2.f * det_sqrt, FEPS));
    float dist = sqrtf(fmaxf(whr, FEPS));
    float scale = 2.f * fmaxf(sqrtf(fmaxf(sqrtf(fmaxf(det_sqrt, FEPS)), FEPS)), FEPS);
    dist = dist / scale;
    float li = 1.f - 1.f / (1.f + log1pf(dist));
    lb[j] = li;
    __syncthreads();

    // rank of li among all 128 (value desc, index asc tie-break)
    int rank = 0;
    #pragma unroll 8
    for (int t = 0; t < NJ; ++t) {
        float o = lb[t];                       // broadcast read, conflict-free
        rank += (o > li || (o == li && t < j)) ? 1 : 0;
    }
    float tot = li;
    float top = (rank < 6) ? li : 0.f;        // 6 largest (keep 122 = ceil(128*.95))

    // wave reduce (64 lanes), then combine the 2 waves via LDS
    #pragma unroll
    for (int d = 32; d > 0; d >>= 1) {
        tot += __shfl_down(tot, d);
        top += __shfl_down(top, d);
    }
    if ((j & 63) == 0) { wtot[j >> 6] = tot; wtop[j >> 6] = top; }
    __syncthreads();
    if (j == 0)
        out[0] = 1.0f * ((wtot[0] + wtot[1]) - (wtop[0] + wtop[1])) / 122.f;  // LOSS_WEIGHT = 1
}

// ---------------------------------------------------------------- launch
extern "C" void kernel_launch(void* const* d_in, const int* in_sizes, int n_in,
                              void* d_out, int out_size, void* d_ws, size_t ws_size,
                              hipStream_t stream) {
    const float* mu        = (const float*)d_in[0];
    const float* sigma     = (const float*)d_in[1];
    const int*   label     = (const int*)d_in[2];
    // d_in[3] = image: unused by the reference's forward pass
    const float* pos_thres = (const float*)d_in[4];
    const float* neg_thres = (const float*)d_in[5];
    float* out = (float*)d_out;

    // workspace: gml only (128 instances x 64B padded lines)
    unsigned* gml = (unsigned*)d_ws;

    hipMemsetAsync(gml, 0, NJ * 16 * sizeof(unsigned), stream);   // stream-ordered, capturable
    k_fused<<<256, 1024, 0, stream>>>(mu, sigma, label, pos_thres, neg_thres, gml);
    k_loss <<<1, 128, 0, stream>>>(sigma, gml, out);
}

// Round 13
// 28.596 us; speedup vs baseline: 1.1115x; 1.1115x over previous
//
#include <hip/hip_runtime.h>
#include <math.h>

#define NJ 128
#define HH 512
#define WW 512
#define FEPS 1e-7f
#define QT  32          // quad tile edge (quads per block side)
#define THS (QT + 2)    // 34: tile + 1-cell halo
#define TLP 36          // padded LDS row pitch

// ---------------------------------------------------------------- eig helper
// 2x2 symmetric eigendecomposition, ascending order (matches jnp.linalg.eigh).
// Bit-identical to validated rounds 2-12.
__device__ __forceinline__ void eig2x2(float a, float b, float c,
                                       float& l0, float& l1,
                                       float& V00, float& V10, float& V01, float& V11) {
    float mean = 0.5f * (a + c);
    float diff = 0.5f * (a - c);
    float disc = sqrtf(diff * diff + b * b);
    l0 = mean - disc;   // smaller
    l1 = mean + disc;   // larger
    float ux, uy;
    if (diff >= 0.f) { ux = diff + disc; uy = b; }
    else             { ux = b;           uy = disc - diff; }
    float nn = sqrtf(ux * ux + uy * uy);
    if (nn > 0.f) { ux /= nn; uy /= nn; } else { ux = 1.f; uy = 0.f; }
    V00 = -uy; V10 = ux;   // column 0 (l0)
    V01 =  ux; V11 = uy;   // column 1 (l1)
}

// ---------------------------------------------------------------- K1: setup-in-LDS + vor
// Validated rounds 9-11; now writes an interleaved float2 {val, bitcast(vor)}
// per pixel (one 8B store instead of two 4B). Block 0 inits gml + bar.
__global__ __launch_bounds__(256, 2) void k_vorf(
        const float* __restrict__ mu, const float* __restrict__ sigma,
        float2* __restrict__ vv, unsigned* __restrict__ gml,
        unsigned* __restrict__ bar) {
    __shared__ float4 lp[NJ];   // mmx, mmy, ia, ib2
    __shared__ float  lic[NJ];  // ic
    int tid = threadIdx.x;
    if (tid < NJ) {
        int j = tid;
        float a = sigma[j * 4 + 0];
        float b = sigma[j * 4 + 1];
        float c = sigma[j * 4 + 3];
        float l0, l1, V00, V10, V01, V11;
        eig2x2(a, b, c, l0, l1, V00, V10, V01, V11);
        float gmean = sqrtf(l0 * l1);
        float lsc0 = l0 / gmean * 4096.f;
        float lsc1 = l1 / gmean * 4096.f;
        float s00 = (V00 * V00 * lsc0 + V01 * V01 * lsc1) * 0.25f;
        float s01 = (V00 * V10 * lsc0 + V01 * V11 * lsc1) * 0.25f;
        float s11 = (V10 * V10 * lsc0 + V11 * V11 * lsc1) * 0.25f;
        float det = s00 * s11 - s01 * s01;
        float4 q;
        q.x = rintf(mu[j * 2 + 0] * 0.5f);   // jnp.round = ties-to-even = rintf
        q.y = rintf(mu[j * 2 + 1] * 0.5f);
        q.z =  s11 / det;                    // ia
        q.w = -2.f * s01 / det;              // ib2
        lp[j]  = q;
        lic[j] = s00 / det;                  // ic
    }
    if (blockIdx.x == 0 && tid < NJ) {       // init atomic table + barrier (stream-ordered)
        gml[tid * 16 + 0] = 0u;
        gml[tid * 16 + 1] = 0u;
        gml[tid * 16 + 2] = 0u;
        if (tid == 0) *bar = 0u;
    }
    __syncthreads();

    int t = blockIdx.x * 256 + tid;          // 0..131071
    int c = t & 511;
    int r = t >> 9;                          // 0..255
    const float SCALE = 512.0f / 511.0f;     // linspace(0, 512, 512) step
    float xc = (float)c * SCALE;
    float ya = (float)r * SCALE;
    float yb = (float)(r + 256) * SCALE;
    float bestA = 3.4e38f, bestB = 3.4e38f;
    int bjA = 0, bjB = 0;
    #pragma unroll 4
    for (int j = 0; j < NJ; ++j) {
        float4 p = lp[j];
        float ic = lic[j];
        float dx  = xc - p.x;
        float dyA = ya - p.y;
        float dyB = yb - p.y;
        float qA = p.z * dx * dx + p.w * dx * dyA + ic * dyA * dyA;
        float qB = p.z * dx * dx + p.w * dx * dyB + ic * dyB * dyB;
        if (qA < bestA) { bestA = qA; bjA = j; }   // first index on ties
        if (qB < bestB) { bestB = qB; bjB = j; }
    }
    float2 wA; wA.x = expf(-0.5f * bestA); wA.y = __int_as_float(bjA);
    float2 wB; wB.x = expf(-0.5f * bestB); wB.y = __int_as_float(bjB);
    vv[r * WW + c] = wA;
    vv[(r + 256) * WW + c] = wB;
}

// ---------------------------------------------------------------- K2: markers + loss
// Round 11 marker kernel (256 blocks x 1024 thr, 1 quad/thread, LDS dedup,
// padded global atomics) + R5's validated last-block loss (rank-select form
// from round 11). Flag flush upgraded to atomicOr (device-scope RMW) since
// it is now read intra-kernel across XCDs; m0/m1 flushes already atomicMax.
__global__ __launch_bounds__(1024) void k_markt(
        const float* __restrict__ mu, const float* __restrict__ sigma,
        const int* __restrict__ label, const float* __restrict__ pos_thres,
        const float* __restrict__ neg_thres,
        const float2* __restrict__ vv,
        unsigned* __restrict__ gml, unsigned* __restrict__ bar,
        float* __restrict__ out) {
    __shared__ float4   lvv[NJ];    // V00, V10, V01, V11
    __shared__ float2   lmu[NJ];    // mux, muy
    __shared__ float    lpt[NJ], lnt[NJ];
    __shared__ float    tval[THS][TLP];
    __shared__ int      tvor[THS][TLP];
    __shared__ unsigned lm0[NJ], lm1[NJ];
    __shared__ int      lflag[NJ];
    __shared__ float    lb[NJ];
    __shared__ float    wtot[2], wtop[2];
    __shared__ int      isLast;

    int tid = threadIdx.x;
    if (tid < NJ) {
        int j = tid;
        float a = sigma[j * 4 + 0];
        float b = sigma[j * 4 + 1];
        float cc = sigma[j * 4 + 3];
        float l0, l1, V00, V10, V01, V11;
        eig2x2(a, b, cc, l0, l1, V00, V10, V01, V11);
        lvv[j] = make_float4(V00, V10, V01, V11);
        lmu[j] = make_float2(mu[j * 2 + 0], mu[j * 2 + 1]);
        int cl = label[j];
        lpt[j] = pos_thres[cl];
        lnt[j] = neg_thres[cl];
        lm0[j] = 0u; lm1[j] = 0u; lflag[j] = 0;
    }

    int A0 = (blockIdx.x >> 4) * QT;   // 16x16 tiles of 32x32 quads
    int B0 = (blockIdx.x & 15) * QT;

    // ---- stage 34x34 halo tile (one coalesced 8B load per cell; OOB -> 0/0)
    for (int idx = tid; idx < THS * THS; idx += 1024) {
        int hu = idx / THS, hw = idx - hu * THS;
        int gy = A0 + hu - 1, gx = B0 + hw - 1;
        float v0 = 0.f; int j0 = 0;
        if (gy >= 0 && gy < HH && gx >= 0 && gx < WW) {
            float2 tv = vv[gy * WW + gx];
            v0 = tv.x; j0 = __float_as_int(tv.y);
        }
        tval[hu][hw] = v0; tvor[hu][hw] = j0;
    }
    __syncthreads();

    // ---- markers (validated round 11, 1 quad/thread)
    int lane = tid & 63;
    {
        int u = tid >> 5;                    // 0..31
        int v = tid & 31;                    // 0..31
        int a = A0 + u, b = B0 + v;
        bool aM = a > 0, aP = a < 511, bM = b > 0, bP = b < 511;
        int hmm_ = (aM && bM) ? tvor[u    ][v    ] : 0;
        int hm0_ =  aM        ? tvor[u    ][v + 1] : 0;
        int hm1_ = (aM && bP) ? tvor[u    ][v + 2] : 0;
        int h0m_ =  bM        ? tvor[u + 1][v    ] : 0;
        int h00_ =              tvor[u + 1][v + 1];
        int h0p_ =  bP        ? tvor[u + 1][v + 2] : 0;
        int hpm_ = (aP && bM) ? tvor[u + 2][v    ] : 0;
        int hp0_ =  aP        ? tvor[u + 2][v + 1] : 0;
        int hpp_ = (aP && bP) ? tvor[u + 2][v + 2] : 0;
        // exact-int Laplacian (3x3 ones, center -8, zero-padded) per full-res pixel
        int lap00 = -5 * h00_ + hmm_ + 2 * hm0_ + 2 * h0m_;
        int lap01 = -5 * h00_ + 2 * hm0_ + hm1_ + 2 * h0p_;
        int lap10 = -5 * h00_ + 2 * h0m_ + hpm_ + 2 * hp0_;
        int lap11 = -5 * h00_ + 2 * h0p_ + 2 * hp0_ + hpp_;
        int hv = h00_;
        float  pt = lpt[hv], nt = lnt[hv];
        float4 Vv = lvv[hv];
        float2 mv = lmu[hv];
        float m0 = -1.f, m1 = -1.f;   // r0,r1 >= 0, so -1 == "no valid pixel yet"

#define DO_PIXEL(U, V, LAP) {                                                  \
    int i = 2 * a + (U), jx = 2 * b + (V);                                     \
    float ry = ((float)i  * 511.0f) / 1023.0f;                                 \
    float rx = ((float)jx * 511.0f) / 1023.0f;                                 \
    int y0 = (int)ry; int y1 = min(y0 + 1, 511); float wy = ry - (float)y0;    \
    int x0 = (int)rx; int x1 = min(x0 + 1, 511); float wx = rx - (float)x0;    \
    int ly0 = y0 - A0 + 1, ly1 = y1 - A0 + 1;                                  \
    int lx0 = x0 - B0 + 1, lx1 = x1 - B0 + 1;                                  \
    float top = tval[ly0][lx0] * (1.f - wx) + tval[ly0][lx1] * wx;             \
    float bot = tval[ly1][lx0] * (1.f - wx) + tval[ly1][lx1] * wx;             \
    float vf  = top * (1.f - wy) + bot * wy;                                   \
    int mk = hv + 1;                                                           \
    if (vf < pt)     mk = 0;                                                   \
    if (vf < nt)     mk = NJ + 1;                                              \
    if ((LAP) != 0)  mk = NJ + 1;                                              \
    if (mk >= 1 && mk <= NJ) {                                                 \
        float dx = (float)jx - mv.x, dy = (float)i - mv.y;                     \
        float r0 = fabsf(Vv.x * dx + Vv.y * dy);                               \
        float r1 = fabsf(Vv.z * dx + Vv.w * dy);                               \
        m0 = fmaxf(m0, r0); m1 = fmaxf(m1, r1);                                \
    } }

        DO_PIXEL(0, 0, lap00)
        DO_PIXEL(0, 1, lap01)
        DO_PIXEL(1, 0, lap10)
        DO_PIXEL(1, 1, lap11)
#undef DO_PIXEL

        // wave segmented prefix-max over contiguous equal-inst runs (validated)
        int inst = (m0 >= 0.f) ? hv : -1;
        #pragma unroll
        for (int d = 1; d < 64; d <<= 1) {
            int   oi = __shfl_up(inst, d);
            float o0 = __shfl_up(m0, d);
            float o1 = __shfl_up(m1, d);
            if (lane >= d && oi == inst) { m0 = fmaxf(m0, o0); m1 = fmaxf(m1, o1); }
        }
        int ni = __shfl_down(inst, 1);
        bool leader = (inst >= 0) && (lane == 63 || ni != inst);
        if (leader) {   // few per wave -> cheap LDS atomics, on-CU
            atomicMax(&lm0[inst], __float_as_uint(m0));
            atomicMax(&lm1[inst], __float_as_uint(m1));
            lflag[inst] = 1;    // benign race, same value
        }
    }
    __syncthreads();

    // one global atomic triple per touched instance per block (padded lines);
    // all device-scope RMW so the last block's coherent reads see them.
    if (tid < NJ && lflag[tid]) {
        atomicMax(&gml[tid * 16 + 0], lm0[tid]);
        atomicMax(&gml[tid * 16 + 1], lm1[tid]);
        atomicOr (&gml[tid * 16 + 2], 1u);
    }

    // ---- last-block-done (validated R5): __syncthreads drains vmcnt, so this
    // block's atomics are at the coherence point before tid0 increments bar.
    __syncthreads();
    if (tid == 0) {
        unsigned done = atomicAdd(bar, 1u);
        isLast = (done == gridDim.x - 1) ? 1 : 0;
    }
    __syncthreads();
    if (!isLast) return;

    // ---------------- loss phase (rank-select, validated round 11; coherent
    // atomic-RMW reads validated R5). All 1024 threads execute the barriers.
    float li = 0.f;
    if (tid < NJ) {
        float aa = sigma[tid * 4 + 0];
        float bb = sigma[tid * 4 + 1];
        float cc = sigma[tid * 4 + 3];
        float ls0, ls1, V00, V10, V01, V11;
        eig2x2(aa, bb, cc, ls0, ls1, V00, V10, V01, V11);
        float g0 = __uint_as_float(atomicMax(&gml[tid * 16 + 0], 0u));
        float g1 = __uint_as_float(atomicMax(&gml[tid * 16 + 1], 0u));
        unsigned has = atomicAdd(&gml[tid * 16 + 2], 0u);
        float lt0 = has ? g0 * g0 : ls0;
        float lt1 = has ? g1 * g1 : ls1;
        float whr = (ls0 + ls1) + (lt0 + lt1);
        float tr  = ls0 * lt0 + ls1 * lt1;
        float det_sqrt = sqrtf(fmaxf((ls0 * ls1) * (lt0 * lt1), FEPS));
        whr = whr - 2.f * sqrtf(fmaxf(tr + 2.f * det_sqrt, FEPS));
        float dist = sqrtf(fmaxf(whr, FEPS));
        float scale = 2.f * fmaxf(sqrtf(fmaxf(sqrtf(fmaxf(det_sqrt, FEPS)), FEPS)), FEPS);
        dist = dist / scale;
        li = 1.f - 1.f / (1.f + log1pf(dist));
        lb[tid] = li;
    }
    __syncthreads();
    if (tid < NJ) {
        // rank among all 128 (value desc, index asc tie-break) — broadcast reads
        int rank = 0;
        #pragma unroll 8
        for (int t = 0; t < NJ; ++t) {
            float o = lb[t];
            rank += (o > li || (o == li && t < tid)) ? 1 : 0;
        }
        float tot = li;
        float top = (rank < 6) ? li : 0.f;   // 6 largest (keep 122 = ceil(128*.95))
        #pragma unroll
        for (int d = 32; d > 0; d >>= 1) {
            tot += __shfl_down(tot, d);
            top += __shfl_down(top, d);
        }
        if ((tid & 63) == 0) { wtot[tid >> 6] = tot; wtop[tid >> 6] = top; }
    }
    __syncthreads();
    if (tid == 0)
        out[0] = 1.0f * ((wtot[0] + wtot[1]) - (wtop[0] + wtop[1])) / 122.f;  // LOSS_WEIGHT = 1
}

// ---------------------------------------------------------------- launch
extern "C" void kernel_launch(void* const* d_in, const int* in_sizes, int n_in,
                              void* d_out, int out_size, void* d_ws, size_t ws_size,
                              hipStream_t stream) {
    const float* mu        = (const float*)d_in[0];
    const float* sigma     = (const float*)d_in[1];
    const int*   label     = (const int*)d_in[2];
    // d_in[3] = image: unused by the reference's forward pass
    const float* pos_thres = (const float*)d_in[4];
    const float* neg_thres = (const float*)d_in[5];
    float* out = (float*)d_out;

    // workspace layout
    float2*   vv  = (float2*)d_ws;                                  // 512*512 float2 (2 MiB)
    unsigned* gml = (unsigned*)((char*)d_ws + 2ull * HH * WW * 4);  // 128 * 16 u32 (64B/inst)
    unsigned* bar = gml + NJ * 16;                                  // 1 u32

    k_vorf <<<(HH * WW / 2) / 256, 256, 0, stream>>>(mu, sigma, vv, gml, bar);
    k_markt<<<256, 1024, 0, stream>>>(mu, sigma, label, pos_thres, neg_thres,
                                      vv, gml, bar, out);
}

// Round 14
// 26.907 us; speedup vs baseline: 1.1813x; 1.0628x over previous
//
#include <hip/hip_runtime.h>
#include <math.h>

#define NJ 128
#define HH 512
#define WW 512
#define FEPS 1e-7f
#define QT  32          // quad tile edge (quads per block side)
#define THS (QT + 2)    // 34: tile + 1-cell halo
#define TLP 36          // padded LDS row pitch

// ---------------------------------------------------------------- eig helper
// 2x2 symmetric eigendecomposition, ascending order (matches jnp.linalg.eigh).
// Bit-identical to validated rounds 2-13.
__device__ __forceinline__ void eig2x2(float a, float b, float c,
                                       float& l0, float& l1,
                                       float& V00, float& V10, float& V01, float& V11) {
    float mean = 0.5f * (a + c);
    float diff = 0.5f * (a - c);
    float disc = sqrtf(diff * diff + b * b);
    l0 = mean - disc;   // smaller
    l1 = mean + disc;   // larger
    float ux, uy;
    if (diff >= 0.f) { ux = diff + disc; uy = b; }
    else             { ux = b;           uy = disc - diff; }
    float nn = sqrtf(ux * ux + uy * uy);
    if (nn > 0.f) { ux /= nn; uy /= nn; } else { ux = 1.f; uy = 0.f; }
    V00 = -uy; V10 = ux;   // column 0 (l0)
    V01 =  ux; V11 = uy;   // column 1 (l1)
}

// ---------------------------------------------------------------- K1: setup-in-LDS + vor
// R11 kernel verbatim, except the output is an interleaved float2
// {val, bitcast(vor)} per pixel (one 8B store instead of two 4B stores).
// Block 0 inits the padded gml table (stream-ordered before K2/K3).
__global__ __launch_bounds__(256, 2) void k_vorf(
        const float* __restrict__ mu, const float* __restrict__ sigma,
        float2* __restrict__ vv, unsigned* __restrict__ gml) {
    __shared__ float4 lp[NJ];   // mmx, mmy, ia, ib2
    __shared__ float  lic[NJ];  // ic
    int tid = threadIdx.x;
    if (tid < NJ) {
        int j = tid;
        float a = sigma[j * 4 + 0];
        float b = sigma[j * 4 + 1];
        float c = sigma[j * 4 + 3];
        float l0, l1, V00, V10, V01, V11;
        eig2x2(a, b, c, l0, l1, V00, V10, V01, V11);
        float gmean = sqrtf(l0 * l1);
        float lsc0 = l0 / gmean * 4096.f;
        float lsc1 = l1 / gmean * 4096.f;
        float s00 = (V00 * V00 * lsc0 + V01 * V01 * lsc1) * 0.25f;
        float s01 = (V00 * V10 * lsc0 + V01 * V11 * lsc1) * 0.25f;
        float s11 = (V10 * V10 * lsc0 + V11 * V11 * lsc1) * 0.25f;
        float det = s00 * s11 - s01 * s01;
        float4 q;
        q.x = rintf(mu[j * 2 + 0] * 0.5f);   // jnp.round = ties-to-even = rintf
        q.y = rintf(mu[j * 2 + 1] * 0.5f);
        q.z =  s11 / det;                    // ia
        q.w = -2.f * s01 / det;              // ib2
        lp[j]  = q;
        lic[j] = s00 / det;                  // ic
    }
    if (blockIdx.x == 0 && tid < NJ) {       // init padded atomic table (stream-ordered)
        gml[tid * 16 + 0] = 0u;
        gml[tid * 16 + 1] = 0u;
        gml[tid * 16 + 2] = 0u;
    }
    __syncthreads();

    int t = blockIdx.x * 256 + tid;          // 0..131071
    int c = t & 511;
    int r = t >> 9;                          // 0..255
    const float SCALE = 512.0f / 511.0f;     // linspace(0, 512, 512) step
    float xc = (float)c * SCALE;
    float ya = (float)r * SCALE;
    float yb = (float)(r + 256) * SCALE;
    float bestA = 3.4e38f, bestB = 3.4e38f;
    int bjA = 0, bjB = 0;
    #pragma unroll 4
    for (int j = 0; j < NJ; ++j) {
        float4 p = lp[j];
        float ic = lic[j];
        float dx  = xc - p.x;
        float dyA = ya - p.y;
        float dyB = yb - p.y;
        float qA = p.z * dx * dx + p.w * dx * dyA + ic * dyA * dyA;
        float qB = p.z * dx * dx + p.w * dx * dyB + ic * dyB * dyB;
        if (qA < bestA) { bestA = qA; bjA = j; }   // first index on ties
        if (qB < bestB) { bestB = qB; bjB = j; }
    }
    float2 wA; wA.x = expf(-0.5f * bestA); wA.y = __int_as_float(bjA);
    float2 wB; wB.x = expf(-0.5f * bestB); wB.y = __int_as_float(bjB);
    vv[r * WW + c] = wA;
    vv[(r + 256) * WW + c] = wB;
}

// ---------------------------------------------------------------- K2: tiled markers
// R11 kernel verbatim (256 blocks x 1024 thr, 1 quad/thread, LDS dedup,
// <=128 padded global atomics/block), except staging reads the interleaved
// float2 (one coalesced 8B load per cell instead of two scattered 4B).
__global__ __launch_bounds__(1024) void k_markt(
        const float* __restrict__ mu, const float* __restrict__ sigma,
        const int* __restrict__ label, const float* __restrict__ pos_thres,
        const float* __restrict__ neg_thres,
        const float2* __restrict__ vv,
        unsigned* __restrict__ gml) {
    __shared__ float4   lvv[NJ];    // V00, V10, V01, V11
    __shared__ float2   lmu[NJ];    // mux, muy
    __shared__ float    lpt[NJ], lnt[NJ];
    __shared__ float    tval[THS][TLP];
    __shared__ int      tvor[THS][TLP];
    __shared__ unsigned lm0[NJ], lm1[NJ];
    __shared__ int      lflag[NJ];

    int tid = threadIdx.x;
    if (tid < NJ) {
        int j = tid;
        float a = sigma[j * 4 + 0];
        float b = sigma[j * 4 + 1];
        float cc = sigma[j * 4 + 3];
        float l0, l1, V00, V10, V01, V11;
        eig2x2(a, b, cc, l0, l1, V00, V10, V01, V11);
        lvv[j] = make_float4(V00, V10, V01, V11);
        lmu[j] = make_float2(mu[j * 2 + 0], mu[j * 2 + 1]);
        int cl = label[j];
        lpt[j] = pos_thres[cl];
        lnt[j] = neg_thres[cl];
        lm0[j] = 0u; lm1[j] = 0u; lflag[j] = 0;
    }

    int A0 = (blockIdx.x >> 4) * QT;   // 16x16 tiles of 32x32 quads
    int B0 = (blockIdx.x & 15) * QT;

    // ---- stage 34x34 halo tile (one coalesced 8B load per cell; OOB -> 0/0)
    for (int idx = tid; idx < THS * THS; idx += 1024) {
        int hu = idx / THS, hw = idx - hu * THS;
        int gy = A0 + hu - 1, gx = B0 + hw - 1;
        float v0 = 0.f; int j0 = 0;
        if (gy >= 0 && gy < HH && gx >= 0 && gx < WW) {
            float2 tv = vv[gy * WW + gx];
            v0 = tv.x; j0 = __float_as_int(tv.y);
        }
        tval[hu][hw] = v0; tvor[hu][hw] = j0;
    }
    __syncthreads();

    // ---- markers (validated rounds 11-13, 1 quad/thread)
    int lane = tid & 63;
    {
        int u = tid >> 5;                    // 0..31
        int v = tid & 31;                    // 0..31
        int a = A0 + u, b = B0 + v;
        bool aM = a > 0, aP = a < 511, bM = b > 0, bP = b < 511;
        int hmm_ = (aM && bM) ? tvor[u    ][v    ] : 0;
        int hm0_ =  aM        ? tvor[u    ][v + 1] : 0;
        int hm1_ = (aM && bP) ? tvor[u    ][v + 2] : 0;
        int h0m_ =  bM        ? tvor[u + 1][v    ] : 0;
        int h00_ =              tvor[u + 1][v + 1];
        int h0p_ =  bP        ? tvor[u + 1][v + 2] : 0;
        int hpm_ = (aP && bM) ? tvor[u + 2][v    ] : 0;
        int hp0_ =  aP        ? tvor[u + 2][v + 1] : 0;
        int hpp_ = (aP && bP) ? tvor[u + 2][v + 2] : 0;
        // exact-int Laplacian (3x3 ones, center -8, zero-padded) per full-res pixel
        int lap00 = -5 * h00_ + hmm_ + 2 * hm0_ + 2 * h0m_;
        int lap01 = -5 * h00_ + 2 * hm0_ + hm1_ + 2 * h0p_;
        int lap10 = -5 * h00_ + 2 * h0m_ + hpm_ + 2 * hp0_;
        int lap11 = -5 * h00_ + 2 * h0p_ + 2 * hp0_ + hpp_;
        int hv = h00_;
        float  pt = lpt[hv], nt = lnt[hv];
        float4 Vv = lvv[hv];
        float2 mv = lmu[hv];
        float m0 = -1.f, m1 = -1.f;   // r0,r1 >= 0, so -1 == "no valid pixel yet"

#define DO_PIXEL(U, V, LAP) {                                                  \
    int i = 2 * a + (U), jx = 2 * b + (V);                                     \
    float ry = ((float)i  * 511.0f) / 1023.0f;                                 \
    float rx = ((float)jx * 511.0f) / 1023.0f;                                 \
    int y0 = (int)ry; int y1 = min(y0 + 1, 511); float wy = ry - (float)y0;    \
    int x0 = (int)rx; int x1 = min(x0 + 1, 511); float wx = rx - (float)x0;    \
    int ly0 = y0 - A0 + 1, ly1 = y1 - A0 + 1;                                  \
    int lx0 = x0 - B0 + 1, lx1 = x1 - B0 + 1;                                  \
    float top = tval[ly0][lx0] * (1.f - wx) + tval[ly0][lx1] * wx;             \
    float bot = tval[ly1][lx0] * (1.f - wx) + tval[ly1][lx1] * wx;             \
    float vf  = top * (1.f - wy) + bot * wy;                                   \
    int mk = hv + 1;                                                           \
    if (vf < pt)     mk = 0;                                                   \
    if (vf < nt)     mk = NJ + 1;                                              \
    if ((LAP) != 0)  mk = NJ + 1;                                              \
    if (mk >= 1 && mk <= NJ) {                                                 \
        float dx = (float)jx - mv.x, dy = (float)i - mv.y;                     \
        float r0 = fabsf(Vv.x * dx + Vv.y * dy);                               \
        float r1 = fabsf(Vv.z * dx + Vv.w * dy);                               \
        m0 = fmaxf(m0, r0); m1 = fmaxf(m1, r1);                                \
    } }

        DO_PIXEL(0, 0, lap00)
        DO_PIXEL(0, 1, lap01)
        DO_PIXEL(1, 0, lap10)
        DO_PIXEL(1, 1, lap11)
#undef DO_PIXEL

        // wave segmented prefix-max over contiguous equal-inst runs (validated)
        int inst = (m0 >= 0.f) ? hv : -1;
        #pragma unroll
        for (int d = 1; d < 64; d <<= 1) {
            int   oi = __shfl_up(inst, d);
            float o0 = __shfl_up(m0, d);
            float o1 = __shfl_up(m1, d);
            if (lane >= d && oi == inst) { m0 = fmaxf(m0, o0); m1 = fmaxf(m1, o1); }
        }
        int ni = __shfl_down(inst, 1);
        bool leader = (inst >= 0) && (lane == 63 || ni != inst);
        if (leader) {   // few per wave -> cheap LDS atomics, on-CU
            atomicMax(&lm0[inst], __float_as_uint(m0));
            atomicMax(&lm1[inst], __float_as_uint(m1));
            lflag[inst] = 1;    // benign race, same value
        }
    }
    __syncthreads();

    // one global atomic triple per touched instance per block, padded lines
    if (tid < NJ && lflag[tid]) {
        atomicMax(&gml[tid * 16 + 0], lm0[tid]);
        atomicMax(&gml[tid * 16 + 1], lm1[tid]);
        gml[tid * 16 + 2] = 1u;   // benign race, same value; visible at dispatch end
    }
}

// ---------------------------------------------------------------- K3: loss + bottom-122 mean
// VERBATIM round 11 (validated rank-select version).
__global__ __launch_bounds__(128) void k_loss(
        const float* __restrict__ sigma, const unsigned* __restrict__ gml,
        float* __restrict__ out) {
    __shared__ float lb[NJ];
    __shared__ float wtot[2], wtop[2];
    int j = threadIdx.x;

    float aa = sigma[j * 4 + 0];
    float bb = sigma[j * 4 + 1];
    float cc = sigma[j * 4 + 3];
    float ls0, ls1, V00, V10, V01, V11;
    eig2x2(aa, bb, cc, ls0, ls1, V00, V10, V01, V11);
    float g0 = __uint_as_float(gml[j * 16 + 0]);
    float g1 = __uint_as_float(gml[j * 16 + 1]);
    bool has = gml[j * 16 + 2] > 0u;
    float lt0 = has ? g0 * g0 : ls0;
    float lt1 = has ? g1 * g1 : ls1;
    float whr = (ls0 + ls1) + (lt0 + lt1);
    float tr  = ls0 * lt0 + ls1 * lt1;
    float det_sqrt = sqrtf(fmaxf((ls0 * ls1) * (lt0 * lt1), FEPS));
    whr = whr - 2.f * sqrtf(fmaxf(tr + 2.f * det_sqrt, FEPS));
    float dist = sqrtf(fmaxf(whr, FEPS));
    float scale = 2.f * fmaxf(sqrtf(fmaxf(sqrtf(fmaxf(det_sqrt, FEPS)), FEPS)), FEPS);
    dist = dist / scale;
    float li = 1.f - 1.f / (1.f + log1pf(dist));
    lb[j] = li;
    __syncthreads();

    // rank of li among all 128 (value desc, index asc tie-break)
    int rank = 0;
    #pragma unroll 8
    for (int t = 0; t < NJ; ++t) {
        float o = lb[t];                       // broadcast read, conflict-free
        rank += (o > li || (o == li && t < j)) ? 1 : 0;
    }
    float tot = li;
    float top = (rank < 6) ? li : 0.f;        // 6 largest (keep 122 = ceil(128*.95))

    // wave reduce (64 lanes), then combine the 2 waves via LDS
    #pragma unroll
    for (int d = 32; d > 0; d >>= 1) {
        tot += __shfl_down(tot, d);
        top += __shfl_down(top, d);
    }
    if ((j & 63) == 0) { wtot[j >> 6] = tot; wtop[j >> 6] = top; }
    __syncthreads();
    if (j == 0)
        out[0] = 1.0f * ((wtot[0] + wtot[1]) - (wtop[0] + wtop[1])) / 122.f;  // LOSS_WEIGHT = 1
}

// ---------------------------------------------------------------- launch
extern "C" void kernel_launch(void* const* d_in, const int* in_sizes, int n_in,
                              void* d_out, int out_size, void* d_ws, size_t ws_size,
                              hipStream_t stream) {
    const float* mu        = (const float*)d_in[0];
    const float* sigma     = (const float*)d_in[1];
    const int*   label     = (const int*)d_in[2];
    // d_in[3] = image: unused by the reference's forward pass
    const float* pos_thres = (const float*)d_in[4];
    const float* neg_thres = (const float*)d_in[5];
    float* out = (float*)d_out;

    // workspace layout
    float2*   vv  = (float2*)d_ws;                                  // 512*512 float2 (2 MiB)
    unsigned* gml = (unsigned*)((char*)d_ws + 2ull * HH * WW * 4);  // 128 * 16 u32 (64B/inst)

    k_vorf <<<(HH * WW / 2) / 256, 256, 0, stream>>>(mu, sigma, vv, gml);
    k_markt<<<256, 1024, 0, stream>>>(mu, sigma, label, pos_thres, neg_thres,
                                      vv, gml);
    k_loss <<<1, 128, 0, stream>>>(sigma, gml, out);
}